// Round 11
// baseline (539.572 us; speedup 1.0000x reference)
//
#include <hip/hip_runtime.h>
#include <hip/hip_fp16.h>
#include <math.h>

#define NSEG 126
#define PI_F 3.14159265358979323846f

__device__ __forceinline__ unsigned bitrev8(unsigned v) { return __brev(v) >> 24; }
__device__ __forceinline__ unsigned bitrev6(unsigned v) { return __brev(v) >> 26; }
__device__ __forceinline__ float2 cmulc(float2 a, float2 b) {
    return make_float2(a.x*b.x - a.y*b.y, a.x*b.y + a.y*b.x);
}
__device__ __forceinline__ float2 mulmi(float2 a){ return make_float2(a.y, -a.x); }

// ---------------------------------------------------------------------------
// One cross-lane DIF stage. Pair distance = hl lanes (butterfly span 4*hl).
// w[i] = w0 * step_i (steps are compile-time constants).
// ---------------------------------------------------------------------------
template <int K>
__device__ __forceinline__ void stage_shfl(float2 x[][4], int lane, int hl,
                                           float2 w0, float2 st1, float2 st2, float2 st3)
{
    float2 w1 = cmulc(w0, st1), w2 = cmulc(w0, st2), w3 = cmulc(w0, st3);
    bool up = (lane & hl) != 0;
    #pragma unroll
    for (int k = 0; k < K; k++) {
        #pragma unroll
        for (int i = 0; i < 4; i++) {
            float2 wi = (i == 0) ? w0 : (i == 1) ? w1 : (i == 2) ? w2 : w3;
            float px = __shfl_xor(x[k][i].x, hl);
            float py = __shfl_xor(x[k][i].y, hl);
            if (up) {
                float dx = px - x[k][i].x, dy = py - x[k][i].y;
                x[k][i] = make_float2(dx*wi.x - dy*wi.y, dx*wi.y + dy*wi.x);
            } else {
                x[k][i] = make_float2(x[k][i].x + px, x[k][i].y + py);
            }
        }
    }
}

// ---------------------------------------------------------------------------
// 256-pt DIF FFT, layout: position p = 4*lane + i, natural-order input.
// On exit x[k][i] = X[bitrev8(4*lane+i)]. Only 4 sincos per call (shared
// over K). Loads/stores at position p are CONTIGUOUS per lane (float4-able).
// ---------------------------------------------------------------------------
template <int K>
__device__ __forceinline__ void fft256_v2(float2 x[][4], int lane) {
    { float s,c; __sincosf(-PI_F*(float)(lane&31)*(1.0f/32.0f), &s,&c);   // h=128
      stage_shfl<K>(x,lane,32, make_float2(c,s),
        make_float2(0.99969882f,-0.02454123f),
        make_float2(0.99879546f,-0.04906767f),
        make_float2(0.99729046f,-0.07356456f)); }
    { float s,c; __sincosf(-PI_F*(float)(lane&15)*(1.0f/16.0f), &s,&c);   // h=64
      stage_shfl<K>(x,lane,16, make_float2(c,s),
        make_float2(0.99879546f,-0.04906767f),
        make_float2(0.99518473f,-0.09801714f),
        make_float2(0.98917651f,-0.14673047f)); }
    { float s,c; __sincosf(-PI_F*(float)(lane&7)*(1.0f/8.0f), &s,&c);     // h=32
      stage_shfl<K>(x,lane,8, make_float2(c,s),
        make_float2(0.99518473f,-0.09801714f),
        make_float2(0.98078528f,-0.19509032f),
        make_float2(0.95694034f,-0.29028468f)); }
    { float s,c; __sincosf(-PI_F*(float)(lane&3)*(1.0f/4.0f), &s,&c);     // h=16
      stage_shfl<K>(x,lane,4, make_float2(c,s),
        make_float2(0.98078528f,-0.19509032f),
        make_float2(0.92387953f,-0.38268343f),
        make_float2(0.83146961f,-0.55557023f)); }
    { float2 w0 = (lane&1) ? make_float2(0.f,-1.f) : make_float2(1.f,0.f); // h=8
      stage_shfl<K>(x,lane,2, w0,
        make_float2(0.92387953f,-0.38268343f),
        make_float2(0.70710678f,-0.70710678f),
        make_float2(0.38268343f,-0.92387953f)); }
    { stage_shfl<K>(x,lane,1, make_float2(1.f,0.f),                        // h=4
        make_float2(0.70710678f,-0.70710678f),
        make_float2(0.f,-1.f),
        make_float2(-0.70710678f,-0.70710678f)); }
    #pragma unroll
    for (int k = 0; k < K; k++) {                                          // h=2, h=1
        float2 u, v;
        u=x[k][0]; v=x[k][2]; x[k][0]=make_float2(u.x+v.x,u.y+v.y); x[k][2]=make_float2(u.x-v.x,u.y-v.y);
        u=x[k][1]; v=x[k][3]; x[k][1]=make_float2(u.x+v.x,u.y+v.y); x[k][3]=mulmi(make_float2(u.x-v.x,u.y-v.y));
        u=x[k][0]; v=x[k][1]; x[k][0]=make_float2(u.x+v.x,u.y+v.y); x[k][1]=make_float2(u.x-v.x,u.y-v.y);
        u=x[k][2]; v=x[k][3]; x[k][2]=make_float2(u.x+v.x,u.y+v.y); x[k][3]=make_float2(u.x-v.x,u.y-v.y);
    }
}

// ---------------------------------------------------------------------------
// Fused prep (R9-proven), b_pack now NATURAL indices (r, 256-r, seg).
// ---------------------------------------------------------------------------
__global__ __launch_bounds__(1024) void prep_all(
    const int* __restrict__ rr, const int* __restrict__ cc,
    const int* __restrict__ seg, int n,
    int* __restrict__ starts, int* __restrict__ b_pack, float* __restrict__ acc)
{
    __shared__ int cnt[128];
    __shared__ int cur[128];
    int tid = threadIdx.x;
    if (tid < NSEG * 3) acc[tid] = 0.f;
    if (tid < 128) cnt[tid] = 0;
    __syncthreads();
    for (int i = tid; i < n; i += 1024) {
        int c = cc[i], r = rr[i];
        if ((c > 128) || (c == 128 && r > 128)) atomicAdd(&cnt[255 - c], 1);
    }
    __syncthreads();
    if (tid < 64) {
        int2 c2 = reinterpret_cast<const int2*>(cnt)[tid];
        int lsum = c2.x + c2.y;
        int pre = lsum;
        #pragma unroll
        for (int off = 1; off < 64; off <<= 1) {
            int v = __shfl_up(pre, off);
            if (tid >= off) pre += v;
        }
        int excl = pre - lsum;
        int2 outv = make_int2(excl, excl + c2.x);
        reinterpret_cast<int2*>(cur)[tid] = outv;
        reinterpret_cast<int2*>(starts)[tid] = outv;
        if (tid == 63) starts[128] = excl + c2.x + c2.y;
    }
    __syncthreads();
    for (int i = tid; i < n; i += 1024) {
        int c = cc[i], r = rr[i];
        if ((c > 128) || (c == 128 && r > 128)) {
            int j = 255 - c;
            int pos = atomicAdd(&cur[j], 1);
            b_pack[pos] = r | (((256 - r) & 255) << 8) | (seg[i] << 16);
        }
    }
}

// ---------------------------------------------------------------------------
// Row-pass: packed z = in + i*tgt; 4 rows/wave (float4 loads), 8 waves =
// 32 rows/block, 8 blocks/pair. T tile in fp16; G[q][x] = X_x[bitrev8(q)].
// ---------------------------------------------------------------------------
__global__ __launch_bounds__(512, 1) void rowfft_kernel(
    const float* __restrict__ inp, const float* __restrict__ tgt,
    __half2* __restrict__ G, int pair_base)
{
    __shared__ __half2 T[256 * 17];              // 17408 B
    int tid    = threadIdx.x;
    int wv     = tid >> 6;
    int lane   = tid & 63;
    int plocal = blockIdx.x >> 3;
    int rowgrp = blockIdx.x & 7;                  // 32 rows each
    int row0   = (rowgrp << 5) + (wv << 2);
    size_t base = (((size_t)(pair_base + plocal)) << 16) + ((size_t)row0 << 8);
    const float4* s1 = (const float4*)(inp + base);
    const float4* s2 = (const float4*)(tgt + base);

    float4 A[4], B[4];
    #pragma unroll
    for (int k = 0; k < 4; k++) { A[k] = s1[k * 64 + lane]; B[k] = s2[k * 64 + lane]; }
    float2 x[4][4];
    #pragma unroll
    for (int k = 0; k < 4; k++) {
        x[k][0] = make_float2(A[k].x, B[k].x);
        x[k][1] = make_float2(A[k].y, B[k].y);
        x[k][2] = make_float2(A[k].z, B[k].z);
        x[k][3] = make_float2(A[k].w, B[k].w);
    }
    fft256_v2<4>(x, lane);

    __half2* dst = G + (((size_t)plocal) << 16) + (rowgrp << 5);
    #pragma unroll
    for (int pass = 0; pass < 2; pass++) {
        if ((wv >> 2) == pass) {                  // waves 0-3 then 4-7
            int xr = ((wv & 3) << 2);
            #pragma unroll
            for (int k = 0; k < 4; k++)
                #pragma unroll
                for (int i = 0; i < 4; i++)
                    T[(4 * lane + i) * 17 + xr + k] = __float22half2_rn(x[k][i]);
        }
        __syncthreads();
        int xl = tid & 15;
        int qq = tid >> 4;                        // 0..31
        #pragma unroll
        for (int ii = 0; ii < 8; ii++) {
            int q = qq + (ii << 5);
            dst[q * 256 + (pass << 4) + xl] = T[q * 17 + xl];
        }
        __syncthreads();
    }
}

// ---------------------------------------------------------------------------
// Column-pass + gather. 512 thr = 8 waves, 4 blocks/pair. Wave owns 4
// buckets = 8 columns; each column = ONE dwordx4 per lane. fft256_v2<8>
// (8-way ILP), un-bitreversed store to per-wave slot, natural-index gather.
// ---------------------------------------------------------------------------
__global__ __launch_bounds__(512, 1) void colfft_gather_kernel(
    const __half2* __restrict__ G, const int* __restrict__ starts,
    const int* __restrict__ b_pack, float* __restrict__ acc)
{
    __shared__ float2 Fb[8 * 512];               // 32 KiB
    __shared__ float accl[NSEG * 3];
    int tid    = threadIdx.x;
    int wv     = tid >> 6;
    int lane   = tid & 63;
    int plocal = blockIdx.x >> 2;
    int b      = blockIdx.x & 3;
    int jb0    = (b << 5) + (wv << 2);           // wave buckets [jb0, jb0+4)

    for (int i = tid; i < NSEG * 3; i += 512) accl[i] = 0.f;
    __syncthreads();

    const __half2* Gp = G + (((size_t)plocal) << 16);
    float4 raw[8];
    #pragma unroll
    for (int t = 0; t < 4; t++) {
        int j = jb0 + t;
        int q_lo = (int)bitrev8((unsigned)(j + 1));
        int q_hi = (int)bitrev8((unsigned)(255 - j));
        raw[2*t]   = ((const float4*)(Gp + ((size_t)q_lo << 8)))[lane];
        raw[2*t+1] = ((const float4*)(Gp + ((size_t)q_hi << 8)))[lane];
    }
    float2 x[8][4];
    #pragma unroll
    for (int k = 0; k < 8; k++) {
        const __half2* hp = (const __half2*)&raw[k];
        #pragma unroll
        for (int i = 0; i < 4; i++) x[k][i] = __half22float2(hp[i]);
    }

    fft256_v2<8>(x, lane);

    float2* slot = Fb + (wv << 9);               // 4 KiB per wave, reused 4x
    int nb = (int)bitrev6((unsigned)lane);
    const int BR2[4] = {0, 2, 1, 3};
    #pragma unroll
    for (int t = 0; t < 4; t++) {
        #pragma unroll
        for (int i = 0; i < 4; i++) {
            slot[nb + (BR2[i] << 6)]       = x[2*t][i];     // F_lo natural
            slot[256 + nb + (BR2[i] << 6)] = x[2*t+1][i];   // F_hi natural
        }
        int j = jb0 + t;
        int s0 = starts[j], s1 = starts[j + 1];
        int e  = s0 + lane;
        int pk = (e < s1) ? b_pack[e] : 0;
        while (e < s1) {
            int e2  = e + 64;
            int pk2 = (e2 < s1) ? b_pack[e2] : 0;
            float2 a = slot[256 + (pk & 255)];        // Fp(r, c)
            float2 m = slot[(pk >> 8) & 255];         // Fp(-r, -c)
            int sg = pk >> 16;
            float f1x = a.x + m.x, f1y = a.y - m.y;   // 2*F1
            float dx  = a.x - m.x, dy  = a.y + m.y;   // 2i*F2
            atomicAdd(&accl[sg * 3 + 0], f1x * dy - f1y * dx);
            atomicAdd(&accl[sg * 3 + 1], f1x * f1x + f1y * f1y);
            atomicAdd(&accl[sg * 3 + 2], dx * dx + dy * dy);
            e = e2; pk = pk2;
        }
    }
    __syncthreads();

    for (int i = tid; i < NSEG * 3; i += 512) {
        float v = accl[i];
        if (v != 0.f) atomicAdd(&acc[i], v);
    }
}

// ---------------------------------------------------------------------------
// PROBES (same geometry as colfft): load-only / load+FFT / load+gather.
// ---------------------------------------------------------------------------
__global__ __launch_bounds__(512, 1) void probe_load(
    const __half2* __restrict__ G, float* __restrict__ scratch)
{
    int tid = threadIdx.x, wv = tid >> 6, lane = tid & 63;
    int plocal = blockIdx.x >> 2, b = blockIdx.x & 3;
    int jb0 = (b << 5) + (wv << 2);
    const __half2* Gp = G + (((size_t)plocal) << 16);
    float s = 0.f;
    #pragma unroll
    for (int t = 0; t < 4; t++) {
        int j = jb0 + t;
        int q_lo = (int)bitrev8((unsigned)(j + 1));
        int q_hi = (int)bitrev8((unsigned)(255 - j));
        float4 a = ((const float4*)(Gp + ((size_t)q_lo << 8)))[lane];
        float4 c = ((const float4*)(Gp + ((size_t)q_hi << 8)))[lane];
        s += a.x + a.y + a.z + a.w + c.x + c.y + c.z + c.w;
    }
    scratch[(size_t)blockIdx.x * 512 + tid] = s;
}

__global__ __launch_bounds__(512, 1) void probe_fft(
    const __half2* __restrict__ G, float* __restrict__ scratch)
{
    int tid = threadIdx.x, wv = tid >> 6, lane = tid & 63;
    int plocal = blockIdx.x >> 2, b = blockIdx.x & 3;
    int jb0 = (b << 5) + (wv << 2);
    const __half2* Gp = G + (((size_t)plocal) << 16);
    float4 raw[8];
    #pragma unroll
    for (int t = 0; t < 4; t++) {
        int j = jb0 + t;
        int q_lo = (int)bitrev8((unsigned)(j + 1));
        int q_hi = (int)bitrev8((unsigned)(255 - j));
        raw[2*t]   = ((const float4*)(Gp + ((size_t)q_lo << 8)))[lane];
        raw[2*t+1] = ((const float4*)(Gp + ((size_t)q_hi << 8)))[lane];
    }
    float2 x[8][4];
    #pragma unroll
    for (int k = 0; k < 8; k++) {
        const __half2* hp = (const __half2*)&raw[k];
        #pragma unroll
        for (int i = 0; i < 4; i++) x[k][i] = __half22float2(hp[i]);
    }
    fft256_v2<8>(x, lane);
    float s = 0.f;
    #pragma unroll
    for (int k = 0; k < 8; k++)
        #pragma unroll
        for (int i = 0; i < 4; i++) s += x[k][i].x + x[k][i].y;
    scratch[(size_t)blockIdx.x * 512 + tid] = s;
}

__global__ __launch_bounds__(512, 1) void probe_gather(
    const __half2* __restrict__ G, const int* __restrict__ starts,
    const int* __restrict__ b_pack, float* __restrict__ scratch)
{
    __shared__ float2 Fb[8 * 512];
    __shared__ float accl[NSEG * 3];
    int tid = threadIdx.x, wv = tid >> 6, lane = tid & 63;
    int plocal = blockIdx.x >> 2, b = blockIdx.x & 3;
    int jb0 = (b << 5) + (wv << 2);
    for (int i = tid; i < NSEG * 3; i += 512) accl[i] = 0.f;
    __syncthreads();
    const __half2* Gp = G + (((size_t)plocal) << 16);
    float2* slot = Fb + (wv << 9);
    int nb = (int)bitrev6((unsigned)lane);
    const int BR2[4] = {0, 2, 1, 3};
    #pragma unroll
    for (int t = 0; t < 4; t++) {
        int j = jb0 + t;
        int q_lo = (int)bitrev8((unsigned)(j + 1));
        int q_hi = (int)bitrev8((unsigned)(255 - j));
        float4 rl = ((const float4*)(Gp + ((size_t)q_lo << 8)))[lane];
        float4 rh = ((const float4*)(Gp + ((size_t)q_hi << 8)))[lane];
        const __half2* hl = (const __half2*)&rl;
        const __half2* hh = (const __half2*)&rh;
        #pragma unroll
        for (int i = 0; i < 4; i++) {            // NO FFT
            slot[nb + (BR2[i] << 6)]       = __half22float2(hl[i]);
            slot[256 + nb + (BR2[i] << 6)] = __half22float2(hh[i]);
        }
        int s0 = starts[j], s1 = starts[j + 1];
        int e  = s0 + lane;
        int pk = (e < s1) ? b_pack[e] : 0;
        while (e < s1) {
            int e2  = e + 64;
            int pk2 = (e2 < s1) ? b_pack[e2] : 0;
            float2 a = slot[256 + (pk & 255)];
            float2 m = slot[(pk >> 8) & 255];
            int sg = pk >> 16;
            float f1x = a.x + m.x, f1y = a.y - m.y;
            float dx  = a.x - m.x, dy  = a.y + m.y;
            atomicAdd(&accl[sg * 3 + 0], f1x * dy - f1y * dx);
            atomicAdd(&accl[sg * 3 + 1], f1x * f1x + f1y * f1y);
            atomicAdd(&accl[sg * 3 + 2], dx * dx + dy * dy);
            e = e2; pk = pk2;
        }
    }
    __syncthreads();
    float* prow = scratch + (size_t)blockIdx.x * 384;
    for (int i = tid; i < NSEG * 3; i += 512) prow[i] = accl[i];
}

// ---------------------------------------------------------------------------
__global__ void final_kernel(const float* __restrict__ acc, const float* __restrict__ w,
                             float* __restrict__ out, float scale) {
    int lane = threadIdx.x;
    float val = 0.f;
    for (int s = lane; s < NSEG; s += 64) {
        float cr = acc[s * 3 + 0];
        float p1 = acc[s * 3 + 1];
        float p2 = acc[s * 3 + 2];
        float den = p1 * p2;
        float curve = den > 0.f ? fabsf(cr) * rsqrtf(den) : 0.f;
        val += curve * w[s + 1];
    }
    if (lane == 0) val += w[0];
    #pragma unroll
    for (int off = 32; off > 0; off >>= 1) val += __shfl_down(val, off);
    if (lane == 0) out[0] = scale * val;
}

// ---------------------------------------------------------------------------
extern "C" void kernel_launch(void* const* d_in, const int* in_sizes, int n_in,
                              void* d_out, int out_size, void* d_ws, size_t ws_size,
                              hipStream_t stream)
{
    const float* inp = (const float*)d_in[0];
    const float* tgt = (const float*)d_in[1];
    const float* wts = (const float*)d_in[2];
    const int*   rr  = (const int*)d_in[3];
    const int*   cc  = (const int*)d_in[4];
    const int*   sg  = (const int*)d_in[5];
    int npts   = in_sizes[3];
    int npairs = in_sizes[0] >> 16;               // B*C (65536 px/img)

    char* ws = (char*)d_ws;
    float* acc    = (float*)(ws + 0);             // 378 floats
    int*   starts = (int*)(ws + 2048);            // 129 ints
    int*   b_pack = (int*)(ws + 4096);
    size_t psoff = 4096 + (size_t)npts * 4;
    psoff = (psoff + 255) & ~(size_t)255;
    float* pscr = (float*)(ws + psoff);           // probe scratch 768*512 floats
    size_t goff = psoff + (size_t)768 * 512 * 4;
    goff = (goff + 255) & ~(size_t)255;
    __half2* G = (__half2*)(ws + goff);

    size_t per_pair = (size_t)256 * 256 * sizeof(__half2);  // 256 KiB
    int maxchunk = (int)((ws_size > goff ? (ws_size - goff) : 0) / per_pair);
    if (maxchunk < 1) maxchunk = 1;
    if (maxchunk > npairs) maxchunk = npairs;

    prep_all<<<1, 1024, 0, stream>>>(rr, cc, sg, npts, starts, b_pack, acc);

    for (int pb = 0; pb < npairs; pb += maxchunk) {
        int cp = npairs - pb < maxchunk ? npairs - pb : maxchunk;
        rowfft_kernel<<<cp * 8, 512, 0, stream>>>(inp, tgt, G, pb);
        colfft_gather_kernel<<<cp * 4, 512, 0, stream>>>(G, starts, b_pack, acc);
        if (pb == 0) {
            probe_load<<<cp * 4, 512, 0, stream>>>(G, pscr);
            probe_load<<<cp * 4, 512, 0, stream>>>(G, pscr);
            probe_fft<<<cp * 4, 512, 0, stream>>>(G, pscr);
            probe_fft<<<cp * 4, 512, 0, stream>>>(G, pscr);
            probe_gather<<<cp * 4, 512, 0, stream>>>(G, starts, b_pack, pscr);
            probe_gather<<<cp * 4, 512, 0, stream>>>(G, starts, b_pack, pscr);
        }
    }

    final_kernel<<<1, 64, 0, stream>>>(acc, wts, (float*)d_out, (float)npairs);
}

// Round 12
// 377.663 us; speedup vs baseline: 1.4287x; 1.4287x over previous
//
#include <hip/hip_runtime.h>
#include <hip/hip_fp16.h>
#include <math.h>

#define NSEG 126
#define PI_F 3.14159265358979323846f
#define TLS 257   // Tl row stride in half2 units (bank-spread)

__device__ __forceinline__ unsigned bitrev8(unsigned v) { return __brev(v) >> 24; }
__device__ __forceinline__ unsigned bitrev6(unsigned v) { return __brev(v) >> 26; }
__device__ __forceinline__ float2 cmulc(float2 a, float2 b) {
    return make_float2(a.x*b.x - a.y*b.y, a.x*b.y + a.y*b.x);
}
__device__ __forceinline__ float2 mulmi(float2 a){ return make_float2(a.y, -a.x); }

// ---------------------------------------------------------------------------
// v2 core (R11-proven): layout p = 4*lane + i, exit x[k][i] = X[bitrev8(p)].
// 4 sincos total, shared across K. Used for the ROW pass (float4 loads).
// ---------------------------------------------------------------------------
template <int K>
__device__ __forceinline__ void stage_shfl(float2 x[][4], int lane, int hl,
                                           float2 w0, float2 st1, float2 st2, float2 st3)
{
    float2 w1 = cmulc(w0, st1), w2 = cmulc(w0, st2), w3 = cmulc(w0, st3);
    bool up = (lane & hl) != 0;
    #pragma unroll
    for (int k = 0; k < K; k++) {
        #pragma unroll
        for (int i = 0; i < 4; i++) {
            float2 wi = (i == 0) ? w0 : (i == 1) ? w1 : (i == 2) ? w2 : w3;
            float px = __shfl_xor(x[k][i].x, hl);
            float py = __shfl_xor(x[k][i].y, hl);
            if (up) {
                float dx = px - x[k][i].x, dy = py - x[k][i].y;
                x[k][i] = make_float2(dx*wi.x - dy*wi.y, dx*wi.y + dy*wi.x);
            } else {
                x[k][i] = make_float2(x[k][i].x + px, x[k][i].y + py);
            }
        }
    }
}

template <int K>
__device__ __forceinline__ void fft256_v2(float2 x[][4], int lane) {
    { float s,c; __sincosf(-PI_F*(float)(lane&31)*(1.0f/32.0f), &s,&c);   // h=128
      stage_shfl<K>(x,lane,32, make_float2(c,s),
        make_float2(0.99969882f,-0.02454123f),
        make_float2(0.99879546f,-0.04906767f),
        make_float2(0.99729046f,-0.07356456f)); }
    { float s,c; __sincosf(-PI_F*(float)(lane&15)*(1.0f/16.0f), &s,&c);   // h=64
      stage_shfl<K>(x,lane,16, make_float2(c,s),
        make_float2(0.99879546f,-0.04906767f),
        make_float2(0.99518473f,-0.09801714f),
        make_float2(0.98917651f,-0.14673047f)); }
    { float s,c; __sincosf(-PI_F*(float)(lane&7)*(1.0f/8.0f), &s,&c);     // h=32
      stage_shfl<K>(x,lane,8, make_float2(c,s),
        make_float2(0.99518473f,-0.09801714f),
        make_float2(0.98078528f,-0.19509032f),
        make_float2(0.95694034f,-0.29028468f)); }
    { float s,c; __sincosf(-PI_F*(float)(lane&3)*(1.0f/4.0f), &s,&c);     // h=16
      stage_shfl<K>(x,lane,4, make_float2(c,s),
        make_float2(0.98078528f,-0.19509032f),
        make_float2(0.92387953f,-0.38268343f),
        make_float2(0.83146961f,-0.55557023f)); }
    { float2 w0 = (lane&1) ? make_float2(0.f,-1.f) : make_float2(1.f,0.f); // h=8
      stage_shfl<K>(x,lane,2, w0,
        make_float2(0.92387953f,-0.38268343f),
        make_float2(0.70710678f,-0.70710678f),
        make_float2(0.38268343f,-0.92387953f)); }
    { stage_shfl<K>(x,lane,1, make_float2(1.f,0.f),                        // h=4
        make_float2(0.70710678f,-0.70710678f),
        make_float2(0.f,-1.f),
        make_float2(-0.70710678f,-0.70710678f)); }
    #pragma unroll
    for (int k = 0; k < K; k++) {                                          // h=2, h=1
        float2 u, v;
        u=x[k][0]; v=x[k][2]; x[k][0]=make_float2(u.x+v.x,u.y+v.y); x[k][2]=make_float2(u.x-v.x,u.y-v.y);
        u=x[k][1]; v=x[k][3]; x[k][1]=make_float2(u.x+v.x,u.y+v.y); x[k][3]=mulmi(make_float2(u.x-v.x,u.y-v.y));
        u=x[k][0]; v=x[k][1]; x[k][0]=make_float2(u.x+v.x,u.y+v.y); x[k][1]=make_float2(u.x-v.x,u.y-v.y);
        u=x[k][2]; v=x[k][3]; x[k][2]=make_float2(u.x+v.x,u.y+v.y); x[k][3]=make_float2(u.x-v.x,u.y-v.y);
    }
}

// ---------------------------------------------------------------------------
// v1 core (R5-proven): layout e = i*64 + lane, exit x[k][i] = X[bitrev8(e)].
// Used for the COL pass (stride-1 LDS reads are conflict-free).
// ---------------------------------------------------------------------------
template <int K>
__device__ __forceinline__ void fftK(float2 x[][4], int lane) {
    {   // stage M=256
        float s, c;
        __sincosf(-PI_F * (float)lane * (1.0f / 128.0f), &s, &c);
        #pragma unroll
        for (int k = 0; k < K; k++) {
            float2 u, t, d;
            u = x[k][0]; t = x[k][2];
            x[k][0] = make_float2(u.x + t.x, u.y + t.y);
            d = make_float2(u.x - t.x, u.y - t.y);
            x[k][2] = make_float2(d.x * c - d.y * s, d.x * s + d.y * c);
            u = x[k][1]; t = x[k][3];
            x[k][1] = make_float2(u.x + t.x, u.y + t.y);
            d = make_float2(u.x - t.x, u.y - t.y);
            x[k][3] = make_float2(d.x * s + d.y * c, -d.x * c + d.y * s); // * (s,-c)
        }
    }
    {   // stage M=128
        float s, c;
        __sincosf(-PI_F * (float)lane * (1.0f / 64.0f), &s, &c);
        #pragma unroll
        for (int k = 0; k < K; k++) {
            float2 u, t, d;
            u = x[k][0]; t = x[k][1];
            x[k][0] = make_float2(u.x + t.x, u.y + t.y);
            d = make_float2(u.x - t.x, u.y - t.y);
            x[k][1] = make_float2(d.x * c - d.y * s, d.x * s + d.y * c);
            u = x[k][2]; t = x[k][3];
            x[k][2] = make_float2(u.x + t.x, u.y + t.y);
            d = make_float2(u.x - t.x, u.y - t.y);
            x[k][3] = make_float2(d.x * c - d.y * s, d.x * s + d.y * c);
        }
    }
    #pragma unroll
    for (int hbit = 5; hbit >= 0; hbit--) {   // stages M=64..2
        int h = 1 << hbit;
        int j = lane & (h - 1);
        float s, c;
        __sincosf(-PI_F * (float)j / (float)h, &s, &c);
        bool up = (lane & h) != 0;
        #pragma unroll
        for (int k = 0; k < K; k++) {
            #pragma unroll
            for (int i = 0; i < 4; i++) {
                float px = __shfl_xor(x[k][i].x, h);
                float py = __shfl_xor(x[k][i].y, h);
                if (up) {
                    float dx = px - x[k][i].x, dy = py - x[k][i].y;
                    x[k][i] = make_float2(dx * c - dy * s, dx * s + dy * c);
                } else {
                    x[k][i] = make_float2(x[k][i].x + px, x[k][i].y + py);
                }
            }
        }
    }
}

// ---------------------------------------------------------------------------
// Fused prep (R9-proven structure): half-plane filter, bucket j = 255-c,
// pack r(8) | slot_lo(7) | slot_hi(7) | seg(7). Mirror index derived in gather.
// ---------------------------------------------------------------------------
__global__ __launch_bounds__(1024) void prep_all(
    const int* __restrict__ rr, const int* __restrict__ cc,
    const int* __restrict__ seg, int n,
    int* __restrict__ starts, int* __restrict__ b_pack, float* __restrict__ acc)
{
    __shared__ int cnt[128];
    __shared__ int cur[128];
    int tid = threadIdx.x;
    if (tid < NSEG * 3) acc[tid] = 0.f;
    if (tid < 128) cnt[tid] = 0;
    __syncthreads();
    for (int i = tid; i < n; i += 1024) {
        int c = cc[i], r = rr[i];
        if ((c > 128) || (c == 128 && r > 128)) atomicAdd(&cnt[255 - c], 1);
    }
    __syncthreads();
    if (tid < 64) {
        int2 c2 = reinterpret_cast<const int2*>(cnt)[tid];
        int lsum = c2.x + c2.y;
        int pre = lsum;
        #pragma unroll
        for (int off = 1; off < 64; off <<= 1) {
            int v = __shfl_up(pre, off);
            if (tid >= off) pre += v;
        }
        int excl = pre - lsum;
        int2 outv = make_int2(excl, excl + c2.x);
        reinterpret_cast<int2*>(cur)[tid] = outv;
        reinterpret_cast<int2*>(starts)[tid] = outv;
        if (tid == 63) starts[128] = excl + c2.x + c2.y;
    }
    __syncthreads();
    for (int i = tid; i < n; i += 1024) {
        int c = cc[i], r = rr[i];
        if ((c > 128) || (c == 128 && r > 128)) {
            int j = 255 - c;
            int pos = atomicAdd(&cur[j], 1);
            int sl, sh;
            if (j < 64) { sl = j;      sh = 127 - j; }
            else        { sl = j - 64; sh = 190 - j; }
            b_pack[pos] = r | (sl << 8) | (sh << 15) | (seg[i] << 22);
        }
    }
}

// ---------------------------------------------------------------------------
// Fused FRC kernel: one block = one pair-half (128 columns entirely in LDS).
//   h=0: cols {1..64} U {192..255} -> buckets 0..63
//   h=1: cols {65..191}            -> buckets 64..127
// Phase 1: 256 row-FFTs (v2, float4 HBM loads), keep own columns in Tl (fp16).
// Phase 2: per-wave column FFTs from Tl (v1 layout, conflict-free), F in place.
// Phase 3: flat gather over this half's b_pack range -> LDS accl -> global acc.
// ---------------------------------------------------------------------------
__global__ __launch_bounds__(1024) void fused_kernel(
    const float* __restrict__ inp, const float* __restrict__ tgt,
    const int* __restrict__ starts, const int* __restrict__ b_pack,
    float* __restrict__ acc)
{
    __shared__ __half2 Tl[128 * TLS];            // 131,584 B
    __shared__ float accl[NSEG * 3];
    int tid  = threadIdx.x;
    int wv   = tid >> 6;
    int lane = tid & 63;
    int pair = blockIdx.x >> 1;
    int h    = blockIdx.x & 1;

    if (tid < NSEG * 3) accl[tid] = 0.f;

    int b6 = (int)bitrev6((unsigned)lane);
    size_t ibase = ((size_t)pair) << 16;

    // ---- phase 1: row FFTs (4 rounds x 4 rows per wave) ----
    for (int rd = 0; rd < 4; rd++) {
        int row0 = (rd << 6) + (wv << 2);
        float2 x[4][4];
        #pragma unroll
        for (int k = 0; k < 4; k++) {
            const float4* s1 = (const float4*)(inp + ibase + (size_t)(row0 + k) * 256);
            const float4* s2 = (const float4*)(tgt + ibase + (size_t)(row0 + k) * 256);
            float4 A = s1[lane], B = s2[lane];
            x[k][0] = make_float2(A.x, B.x);
            x[k][1] = make_float2(A.y, B.y);
            x[k][2] = make_float2(A.z, B.z);
            x[k][3] = make_float2(A.w, B.w);
        }
        fft256_v2<4>(x, lane);
        // natural col of elem i: {b6, 128+b6, 64+b6, 192+b6}
        #pragma unroll
        for (int k = 0; k < 4; k++) {
            int xr = row0 + k;
            if (h == 0) {
                if (b6 >= 1) Tl[(b6 - 1) * TLS + xr] = __float22half2_rn(x[k][0]); // c=b6 in 1..63
                else         Tl[63 * TLS + xr]       = __float22half2_rn(x[k][2]); // c=64
                Tl[(64 + b6) * TLS + xr] = __float22half2_rn(x[k][3]);             // c=192+b6
            } else {
                if (b6 >= 1) Tl[(b6 - 1) * TLS + xr] = __float22half2_rn(x[k][2]); // c=64+b6 in 65..127
                Tl[(63 + b6) * TLS + xr] = __float22half2_rn(x[k][1]);             // c=128+b6 (128->slot63)
            }
        }
    }
    __syncthreads();

    // ---- phase 2: column FFTs, wave w owns slots 8w..8w+7 ----
    {
        float2 y[8][4];
        #pragma unroll
        for (int k = 0; k < 8; k++) {
            const __half2* src = Tl + (wv * 8 + k) * TLS;
            #pragma unroll
            for (int i = 0; i < 4; i++)
                y[k][i] = __half22float2(src[i * 64 + lane]);
        }
        fftK<8>(y, lane);
        #pragma unroll
        for (int k = 0; k < 8; k++) {                   // F stays bitrev-laid-out
            __half2* dst = Tl + (wv * 8 + k) * TLS;
            #pragma unroll
            for (int i = 0; i < 4; i++)
                dst[i * 64 + lane] = __float22half2_rn(y[k][i]);
        }
    }
    __syncthreads();

    // ---- phase 3: flat gather over this half's point range ----
    int s64  = starts[64];
    int sBeg = h ? s64 : 0;
    int sEnd = h ? starts[128] : s64;
    int e  = sBeg + tid;
    int pk = (e < sEnd) ? b_pack[e] : 0;
    while (e < sEnd) {
        int e2  = e + 1024;
        int pk2 = (e2 < sEnd) ? b_pack[e2] : 0;
        int r  = pk & 255;
        int sl = (pk >> 8) & 127;
        int sh = (pk >> 15) & 127;
        int sg = (pk >> 22) & 127;
        int mr = (256 - r) & 255;
        int pr = (int)bitrev8((unsigned)r);
        int pm = (int)bitrev8((unsigned)mr);
        float2 a = __half22float2(Tl[sh * TLS + pr]);   // Fp(r, c)
        float2 m = __half22float2(Tl[sl * TLS + pm]);   // Fp(-r, -c)
        float f1x = a.x + m.x, f1y = a.y - m.y;         // 2*F1
        float dx  = a.x - m.x, dy  = a.y + m.y;         // 2i*F2
        atomicAdd(&accl[sg * 3 + 0], f1x * dy - f1y * dx);
        atomicAdd(&accl[sg * 3 + 1], f1x * f1x + f1y * f1y);
        atomicAdd(&accl[sg * 3 + 2], dx * dx + dy * dy);
        e = e2; pk = pk2;
    }
    __syncthreads();

    if (tid < NSEG * 3) {
        float v = accl[tid];
        if (v != 0.f) atomicAdd(&acc[tid], v);
    }
}

// ---------------------------------------------------------------------------
__global__ void final_kernel(const float* __restrict__ acc, const float* __restrict__ w,
                             float* __restrict__ out, float scale) {
    int lane = threadIdx.x;
    float val = 0.f;
    for (int s = lane; s < NSEG; s += 64) {
        float cr = acc[s * 3 + 0];
        float p1 = acc[s * 3 + 1];
        float p2 = acc[s * 3 + 2];
        float den = p1 * p2;
        float curve = den > 0.f ? fabsf(cr) * rsqrtf(den) : 0.f;
        val += curve * w[s + 1];
    }
    if (lane == 0) val += w[0];
    #pragma unroll
    for (int off = 32; off > 0; off >>= 1) val += __shfl_down(val, off);
    if (lane == 0) out[0] = scale * val;
}

// ---------------------------------------------------------------------------
extern "C" void kernel_launch(void* const* d_in, const int* in_sizes, int n_in,
                              void* d_out, int out_size, void* d_ws, size_t ws_size,
                              hipStream_t stream)
{
    const float* inp = (const float*)d_in[0];
    const float* tgt = (const float*)d_in[1];
    const float* wts = (const float*)d_in[2];
    const int*   rr  = (const int*)d_in[3];
    const int*   cc  = (const int*)d_in[4];
    const int*   sg  = (const int*)d_in[5];
    int npts   = in_sizes[3];
    int npairs = in_sizes[0] >> 16;               // B*C (65536 px/img)

    char* ws = (char*)d_ws;
    float* acc    = (float*)(ws + 0);             // 378 floats
    int*   starts = (int*)(ws + 2048);            // 129 ints
    int*   b_pack = (int*)(ws + 4096);            // npts ints (kept subset)

    prep_all<<<1, 1024, 0, stream>>>(rr, cc, sg, npts, starts, b_pack, acc);
    fused_kernel<<<npairs * 2, 1024, 0, stream>>>(inp, tgt, starts, b_pack, acc);
    final_kernel<<<1, 64, 0, stream>>>(acc, wts, (float*)d_out, (float)npairs);
}

// Round 13
// 238.386 us; speedup vs baseline: 2.2634x; 1.5843x over previous
//
#include <hip/hip_runtime.h>
#include <hip/hip_fp16.h>
#include <math.h>

#define NSEG 126
#define PI_F 3.14159265358979323846f

__device__ __forceinline__ unsigned bitrev8(unsigned v) { return __brev(v) >> 24; }
__device__ __forceinline__ unsigned bitrev6(unsigned v) { return __brev(v) >> 26; }
__device__ __forceinline__ float2 cmulc(float2 a, float2 b) {
    return make_float2(a.x*b.x - a.y*b.y, a.x*b.y + a.y*b.x);
}
__device__ __forceinline__ float2 mulmi(float2 a){ return make_float2(a.y, -a.x); }

// ---------------------------------------------------------------------------
// v2 core (R11-proven): layout p = 4*lane + i, exit x[k][i] = X[bitrev8(p)].
// ---------------------------------------------------------------------------
template <int K>
__device__ __forceinline__ void stage_shfl(float2 x[][4], int lane, int hl,
                                           float2 w0, float2 st1, float2 st2, float2 st3)
{
    float2 w1 = cmulc(w0, st1), w2 = cmulc(w0, st2), w3 = cmulc(w0, st3);
    bool up = (lane & hl) != 0;
    #pragma unroll
    for (int k = 0; k < K; k++) {
        #pragma unroll
        for (int i = 0; i < 4; i++) {
            float2 wi = (i == 0) ? w0 : (i == 1) ? w1 : (i == 2) ? w2 : w3;
            float px = __shfl_xor(x[k][i].x, hl);
            float py = __shfl_xor(x[k][i].y, hl);
            if (up) {
                float dx = px - x[k][i].x, dy = py - x[k][i].y;
                x[k][i] = make_float2(dx*wi.x - dy*wi.y, dx*wi.y + dy*wi.x);
            } else {
                x[k][i] = make_float2(x[k][i].x + px, x[k][i].y + py);
            }
        }
    }
}

template <int K>
__device__ __forceinline__ void fft256_v2(float2 x[][4], int lane) {
    { float s,c; __sincosf(-PI_F*(float)(lane&31)*(1.0f/32.0f), &s,&c);   // h=128
      stage_shfl<K>(x,lane,32, make_float2(c,s),
        make_float2(0.99969882f,-0.02454123f),
        make_float2(0.99879546f,-0.04906767f),
        make_float2(0.99729046f,-0.07356456f)); }
    { float s,c; __sincosf(-PI_F*(float)(lane&15)*(1.0f/16.0f), &s,&c);   // h=64
      stage_shfl<K>(x,lane,16, make_float2(c,s),
        make_float2(0.99879546f,-0.04906767f),
        make_float2(0.99518473f,-0.09801714f),
        make_float2(0.98917651f,-0.14673047f)); }
    { float s,c; __sincosf(-PI_F*(float)(lane&7)*(1.0f/8.0f), &s,&c);     // h=32
      stage_shfl<K>(x,lane,8, make_float2(c,s),
        make_float2(0.99518473f,-0.09801714f),
        make_float2(0.98078528f,-0.19509032f),
        make_float2(0.95694034f,-0.29028468f)); }
    { float s,c; __sincosf(-PI_F*(float)(lane&3)*(1.0f/4.0f), &s,&c);     // h=16
      stage_shfl<K>(x,lane,4, make_float2(c,s),
        make_float2(0.98078528f,-0.19509032f),
        make_float2(0.92387953f,-0.38268343f),
        make_float2(0.83146961f,-0.55557023f)); }
    { float2 w0 = (lane&1) ? make_float2(0.f,-1.f) : make_float2(1.f,0.f); // h=8
      stage_shfl<K>(x,lane,2, w0,
        make_float2(0.92387953f,-0.38268343f),
        make_float2(0.70710678f,-0.70710678f),
        make_float2(0.38268343f,-0.92387953f)); }
    { stage_shfl<K>(x,lane,1, make_float2(1.f,0.f),                        // h=4
        make_float2(0.70710678f,-0.70710678f),
        make_float2(0.f,-1.f),
        make_float2(-0.70710678f,-0.70710678f)); }
    #pragma unroll
    for (int k = 0; k < K; k++) {                                          // h=2, h=1
        float2 u, v;
        u=x[k][0]; v=x[k][2]; x[k][0]=make_float2(u.x+v.x,u.y+v.y); x[k][2]=make_float2(u.x-v.x,u.y-v.y);
        u=x[k][1]; v=x[k][3]; x[k][1]=make_float2(u.x+v.x,u.y+v.y); x[k][3]=mulmi(make_float2(u.x-v.x,u.y-v.y));
        u=x[k][0]; v=x[k][1]; x[k][0]=make_float2(u.x+v.x,u.y+v.y); x[k][1]=make_float2(u.x-v.x,u.y-v.y);
        u=x[k][2]; v=x[k][3]; x[k][2]=make_float2(u.x+v.x,u.y+v.y); x[k][3]=make_float2(u.x-v.x,u.y-v.y);
    }
}

// ---------------------------------------------------------------------------
// Fused prep (R11 format): bucket j = 255-c; pack r | mirror(r)<<8 | seg<<16.
// ---------------------------------------------------------------------------
__global__ __launch_bounds__(1024) void prep_all(
    const int* __restrict__ rr, const int* __restrict__ cc,
    const int* __restrict__ seg, int n,
    int* __restrict__ starts, int* __restrict__ b_pack, float* __restrict__ acc)
{
    __shared__ int cnt[128];
    __shared__ int cur[128];
    int tid = threadIdx.x;
    if (tid < NSEG * 3) acc[tid] = 0.f;
    if (tid < 128) cnt[tid] = 0;
    __syncthreads();
    for (int i = tid; i < n; i += 1024) {
        int c = cc[i], r = rr[i];
        if ((c > 128) || (c == 128 && r > 128)) atomicAdd(&cnt[255 - c], 1);
    }
    __syncthreads();
    if (tid < 64) {
        int2 c2 = reinterpret_cast<const int2*>(cnt)[tid];
        int lsum = c2.x + c2.y;
        int pre = lsum;
        #pragma unroll
        for (int off = 1; off < 64; off <<= 1) {
            int v = __shfl_up(pre, off);
            if (tid >= off) pre += v;
        }
        int excl = pre - lsum;
        int2 outv = make_int2(excl, excl + c2.x);
        reinterpret_cast<int2*>(cur)[tid] = outv;
        reinterpret_cast<int2*>(starts)[tid] = outv;
        if (tid == 63) starts[128] = excl + c2.x + c2.y;
    }
    __syncthreads();
    for (int i = tid; i < n; i += 1024) {
        int c = cc[i], r = rr[i];
        if ((c > 128) || (c == 128 && r > 128)) {
            int j = 255 - c;
            int pos = atomicAdd(&cur[j], 1);
            b_pack[pos] = r | (((256 - r) & 255) << 8) | (seg[i] << 16);
        }
    }
}

// ---------------------------------------------------------------------------
// Row-pass (R11): v2 FFT, float4 loads, fp16 Gt; row q holds X[bitrev8(q)].
// ---------------------------------------------------------------------------
__global__ __launch_bounds__(512, 1) void rowfft_kernel(
    const float* __restrict__ inp, const float* __restrict__ tgt,
    __half2* __restrict__ G, int pair_base)
{
    __shared__ __half2 T[256 * 17];              // 17408 B
    int tid    = threadIdx.x;
    int wv     = tid >> 6;
    int lane   = tid & 63;
    int plocal = blockIdx.x >> 3;
    int rowgrp = blockIdx.x & 7;                  // 32 rows each
    int row0   = (rowgrp << 5) + (wv << 2);
    size_t base = (((size_t)(pair_base + plocal)) << 16) + ((size_t)row0 << 8);
    const float4* s1 = (const float4*)(inp + base);
    const float4* s2 = (const float4*)(tgt + base);

    float4 A[4], B[4];
    #pragma unroll
    for (int k = 0; k < 4; k++) { A[k] = s1[k * 64 + lane]; B[k] = s2[k * 64 + lane]; }
    float2 x[4][4];
    #pragma unroll
    for (int k = 0; k < 4; k++) {
        x[k][0] = make_float2(A[k].x, B[k].x);
        x[k][1] = make_float2(A[k].y, B[k].y);
        x[k][2] = make_float2(A[k].z, B[k].z);
        x[k][3] = make_float2(A[k].w, B[k].w);
    }
    fft256_v2<4>(x, lane);

    __half2* dst = G + (((size_t)plocal) << 16) + (rowgrp << 5);
    #pragma unroll
    for (int pass = 0; pass < 2; pass++) {
        if ((wv >> 2) == pass) {                  // waves 0-3 then 4-7
            int xr = ((wv & 3) << 2);
            #pragma unroll
            for (int k = 0; k < 4; k++)
                #pragma unroll
                for (int i = 0; i < 4; i++)
                    T[(4 * lane + i) * 17 + xr + k] = __float22half2_rn(x[k][i]);
        }
        __syncthreads();
        int xl = tid & 15;
        int qq = tid >> 4;                        // 0..31
        #pragma unroll
        for (int ii = 0; ii < 8; ii++) {
            int q = qq + (ii << 5);
            dst[q * 256 + (pass << 4) + xl] = T[q * 17 + xl];
        }
        __syncthreads();
    }
}

// ---------------------------------------------------------------------------
// Column-pass + gather. R11 structure + REPLICATED accl (8 copies, lane>>3)
// so ring-clustered same-segment LDS atomics hit distinct replicas.
// ---------------------------------------------------------------------------
__global__ __launch_bounds__(512, 1) void colfft_gather_kernel(
    const __half2* __restrict__ G, const int* __restrict__ starts,
    const int* __restrict__ b_pack, float* __restrict__ acc)
{
    __shared__ float2 Fb[8 * 512];               // 32 KiB
    __shared__ float accl[8][NSEG * 3];          // 12,096 B replicated
    int tid    = threadIdx.x;
    int wv     = tid >> 6;
    int lane   = tid & 63;
    int rep    = lane >> 3;                      // 8 lanes per replica
    int plocal = blockIdx.x >> 2;
    int b      = blockIdx.x & 3;
    int jb0    = (b << 5) + (wv << 2);           // wave buckets [jb0, jb0+4)

    for (int i = tid; i < 8 * NSEG * 3; i += 512) ((float*)accl)[i] = 0.f;
    __syncthreads();

    const __half2* Gp = G + (((size_t)plocal) << 16);
    float4 raw[8];
    #pragma unroll
    for (int t = 0; t < 4; t++) {
        int j = jb0 + t;
        int q_lo = (int)bitrev8((unsigned)(j + 1));
        int q_hi = (int)bitrev8((unsigned)(255 - j));
        raw[2*t]   = ((const float4*)(Gp + ((size_t)q_lo << 8)))[lane];
        raw[2*t+1] = ((const float4*)(Gp + ((size_t)q_hi << 8)))[lane];
    }
    float2 x[8][4];
    #pragma unroll
    for (int k = 0; k < 8; k++) {
        const __half2* hp = (const __half2*)&raw[k];
        #pragma unroll
        for (int i = 0; i < 4; i++) x[k][i] = __half22float2(hp[i]);
    }

    fft256_v2<8>(x, lane);

    float2* slot = Fb + (wv << 9);               // 4 KiB per wave, reused 4x
    int nb = (int)bitrev6((unsigned)lane);
    const int BR2[4] = {0, 2, 1, 3};
    #pragma unroll
    for (int t = 0; t < 4; t++) {
        #pragma unroll
        for (int i = 0; i < 4; i++) {
            slot[nb + (BR2[i] << 6)]       = x[2*t][i];     // F_lo natural
            slot[256 + nb + (BR2[i] << 6)] = x[2*t+1][i];   // F_hi natural
        }
        int j = jb0 + t;
        int s0 = starts[j], s1 = starts[j + 1];
        int e  = s0 + lane;
        int pk = (e < s1) ? b_pack[e] : 0;
        while (e < s1) {
            int e2  = e + 64;
            int pk2 = (e2 < s1) ? b_pack[e2] : 0;
            float2 a = slot[256 + (pk & 255)];        // Fp(r, c)
            float2 m = slot[(pk >> 8) & 255];         // Fp(-r, -c)
            int sg = pk >> 16;
            float f1x = a.x + m.x, f1y = a.y - m.y;   // 2*F1
            float dx  = a.x - m.x, dy  = a.y + m.y;   // 2i*F2
            atomicAdd(&accl[rep][sg * 3 + 0], f1x * dy - f1y * dx);
            atomicAdd(&accl[rep][sg * 3 + 1], f1x * f1x + f1y * f1y);
            atomicAdd(&accl[rep][sg * 3 + 2], dx * dx + dy * dy);
            e = e2; pk = pk2;
        }
    }
    __syncthreads();

    for (int i = tid; i < NSEG * 3; i += 512) {
        float v = 0.f;
        #pragma unroll
        for (int rp = 0; rp < 8; rp++) v += accl[rp][i];
        if (v != 0.f) atomicAdd(&acc[i], v);
    }
}

// ---------------------------------------------------------------------------
__global__ void final_kernel(const float* __restrict__ acc, const float* __restrict__ w,
                             float* __restrict__ out, float scale) {
    int lane = threadIdx.x;
    float val = 0.f;
    for (int s = lane; s < NSEG; s += 64) {
        float cr = acc[s * 3 + 0];
        float p1 = acc[s * 3 + 1];
        float p2 = acc[s * 3 + 2];
        float den = p1 * p2;
        float curve = den > 0.f ? fabsf(cr) * rsqrtf(den) : 0.f;
        val += curve * w[s + 1];
    }
    if (lane == 0) val += w[0];
    #pragma unroll
    for (int off = 32; off > 0; off >>= 1) val += __shfl_down(val, off);
    if (lane == 0) out[0] = scale * val;
}

// ---------------------------------------------------------------------------
extern "C" void kernel_launch(void* const* d_in, const int* in_sizes, int n_in,
                              void* d_out, int out_size, void* d_ws, size_t ws_size,
                              hipStream_t stream)
{
    const float* inp = (const float*)d_in[0];
    const float* tgt = (const float*)d_in[1];
    const float* wts = (const float*)d_in[2];
    const int*   rr  = (const int*)d_in[3];
    const int*   cc  = (const int*)d_in[4];
    const int*   sg  = (const int*)d_in[5];
    int npts   = in_sizes[3];
    int npairs = in_sizes[0] >> 16;               // B*C (65536 px/img)

    char* ws = (char*)d_ws;
    float* acc    = (float*)(ws + 0);             // 378 floats
    int*   starts = (int*)(ws + 2048);            // 129 ints
    int*   b_pack = (int*)(ws + 4096);
    size_t goff = 4096 + (size_t)npts * 4;
    goff = (goff + 255) & ~(size_t)255;
    __half2* G = (__half2*)(ws + goff);

    size_t per_pair = (size_t)256 * 256 * sizeof(__half2);  // 256 KiB
    int maxchunk = (int)((ws_size > goff ? (ws_size - goff) : 0) / per_pair);
    if (maxchunk < 1) maxchunk = 1;
    if (maxchunk > npairs) maxchunk = npairs;

    prep_all<<<1, 1024, 0, stream>>>(rr, cc, sg, npts, starts, b_pack, acc);

    for (int pb = 0; pb < npairs; pb += maxchunk) {
        int cp = npairs - pb < maxchunk ? npairs - pb : maxchunk;
        rowfft_kernel<<<cp * 8, 512, 0, stream>>>(inp, tgt, G, pb);
        colfft_gather_kernel<<<cp * 4, 512, 0, stream>>>(G, starts, b_pack, acc);
    }

    final_kernel<<<1, 64, 0, stream>>>(acc, wts, (float*)d_out, (float)npairs);
}